// Round 2
// baseline (158.870 us; speedup 1.0000x reference)
//
#include <hip/hip_runtime.h>

#define NB 8
#define CC 256
#define HH 8
#define DD 32
#define LL 4096

typedef short v8s __attribute__((ext_vector_type(8)));
typedef float v4f __attribute__((ext_vector_type(4)));
typedef unsigned short v8u __attribute__((ext_vector_type(8)));
typedef unsigned short v4us __attribute__((ext_vector_type(4)));

__device__ __forceinline__ float4 ld4(const float* p) { return *(const float4*)p; }

// round-to-nearest-even fp32 -> bf16 (as ushort)
__device__ __forceinline__ unsigned short f2bf(float f) {
    union { float f; unsigned int u; } v; v.f = f;
    unsigned int r = (v.u + 0x7FFFu + ((v.u >> 16) & 1u)) >> 16;
    return (unsigned short)r;
}
__device__ __forceinline__ float bf2f(unsigned short u) {
    union { unsigned int u; float f; } v; v.u = ((unsigned int)u) << 16;
    return v.f;
}

// async global->LDS, 16 B per lane (dest = wave-uniform base + lane*16)
__device__ __forceinline__ void gl_lds16(const unsigned short* g, unsigned short* l) {
    __builtin_amdgcn_global_load_lds(
        (const __attribute__((address_space(1))) void*)g,
        (__attribute__((address_space(3))) void*)l, 16, 0, 0);
}

// ---------------------------------------------------------------------------
// prep_w: weights fp32 -> bf16 only (x-transpose is now fused into the GEMM,
// attn zeroing moved into gemm_qkv's jt==2 blocks).  128 blocks exactly.
// ---------------------------------------------------------------------------
__global__ __launch_bounds__(256) void prep_w(
    const float* __restrict__ wq, const float* __restrict__ wp,
    unsigned short* __restrict__ dwq, unsigned short* __restrict__ dwp)
{
    int ti = blockIdx.x * 256 + threadIdx.x;
    if (ti < 24576) {                       // 3*CC*CC / 8
        int i = ti * 8;
        float4 f0 = ld4(wq + i), f1 = ld4(wq + i + 4);
        v8u o;
        o[0] = f2bf(f0.x); o[1] = f2bf(f0.y); o[2] = f2bf(f0.z); o[3] = f2bf(f0.w);
        o[4] = f2bf(f1.x); o[5] = f2bf(f1.y); o[6] = f2bf(f1.z); o[7] = f2bf(f1.w);
        *(v8u*)(dwq + i) = o;
    } else {                                // CC*CC / 8
        int i = (ti - 24576) * 8;
        float4 f0 = ld4(wp + i), f1 = ld4(wp + i + 4);
        v8u o;
        o[0] = f2bf(f0.x); o[1] = f2bf(f0.y); o[2] = f2bf(f0.z); o[3] = f2bf(f0.w);
        o[4] = f2bf(f1.x); o[5] = f2bf(f1.y); o[6] = f2bf(f1.z); o[7] = f2bf(f1.w);
        *(v8u*)(dwp + i) = o;
    }
}

// ---------------------------------------------------------------------------
// Kernel 1: MFMA qkv GEMM, now consuming x[N,C,L] fp32 DIRECTLY.
// X staging does the transpose in-register: per kt, thread (lw = tid&127,
// half = tid>>7) gathers 8 c-values at fixed l (each instr = 64 consecutive
// l * 4B = 256B coalesced), cvt fp32->bf16, ds_write_b128 into the same
// XOR-swizzled xs[l][ch^(l&7)] layout the MFMA read path uses.
// W staging unchanged (global_load_lds from pre-cvt wqb, pre-swizzled src).
// jt==2 blocks also zero the attn accumulator (1 float/thread).
// ---------------------------------------------------------------------------
__global__ __launch_bounds__(256, 2) void gemm_qkv_mfma(
    const float* __restrict__ x, const unsigned short* __restrict__ wqb,
    const float* __restrict__ bqkv,
    unsigned short* __restrict__ q, unsigned short* __restrict__ k,
    unsigned short* __restrict__ v, float* __restrict__ attn)
{
    __shared__ __align__(16) unsigned short xs[8192];    // 128 l x 64 c (swizzled)
    __shared__ __align__(16) unsigned short wsb[16384];  // 256 j x 64 c (swizzled)

    const int bid  = blockIdx.x;
    const int xcd  = bid & 7;
    const int slot = bid >> 3;        // 0..95
    const int jt   = slot % 3;        // 0=q 1=k 2=v; trio shares (l,n) X-tile
    const int p    = slot / 3;        // 0..31
    const int gp   = xcd * 32 + p;    // 0..255
    const int l0   = (gp & 31) * 128;
    const int n    = gp >> 5;
    const int j0   = jt * 256;

    const int tid = threadIdx.x;
    const int lane = tid & 63, wave = tid >> 6;
    const int wr = wave >> 1, wc = wave & 1;
    const int r = lane & 15, quad = lane >> 4;

    if (jt == 2) attn[gp * 256 + tid] = 0.f;

    // W staging addressing (pre-swizzled global source, linear LDS dest)
    const int srow = wave * 8 + (lane >> 3);
    const int dchunk = (lane & 7) ^ (lane >> 3);
    const unsigned short* wg = wqb + (size_t)(j0 + srow) * CC + dchunk * 8;
    unsigned short* wls = wsb + wave * 512 + lane * 8;

    // X transposed staging addressing
    const int lw = tid & 127;
    const int half = tid >> 7;
    const float* xrow = x + (size_t)n * CC * LL + l0 + lw;   // + c*LL per column

    v4f acc[8][4];
#pragma unroll
    for (int mi = 0; mi < 8; ++mi)
#pragma unroll
        for (int nj = 0; nj < 4; ++nj) acc[mi][nj] = (v4f)(0.f);

    const int jbase = wr * 128;
    const int lbase = wc * 64;

    for (int kt = 0; kt < 4; ++kt) {
        if (kt) __syncthreads();
        const int c0 = kt * 64;
        // issue async W loads first so HBM latency overlaps the X transpose
#pragma unroll
        for (int i = 0; i < 8; ++i)
            gl_lds16(wg + (size_t)i * 32 * CC + c0, wls + i * 2048);
        // X: gather 4 chunks of 8 c at fixed l, cvt, swizzled b128 write
#pragma unroll
        for (int chi = 0; chi < 4; ++chi) {
            int ch = half * 4 + chi;
            const float* src = xrow + (size_t)(c0 + ch * 8) * LL;
            float f[8];
#pragma unroll
            for (int j = 0; j < 8; ++j) f[j] = src[(size_t)j * LL];
            v8u o;
#pragma unroll
            for (int j = 0; j < 8; ++j) o[j] = f2bf(f[j]);
            *(v8u*)(xs + lw * 64 + ((ch ^ (lw & 7)) * 8)) = o;
        }
        __syncthreads();

#pragma unroll
        for (int kk = 0; kk < 2; ++kk) {
            const int cfrag = kk * 4 + quad;
            const int s = cfrag ^ (r & 7);
            v8s b[4];
#pragma unroll
            for (int nj = 0; nj < 4; ++nj) {
                int lloc = lbase + nj * 16 + r;
                b[nj] = *(const v8s*)(xs + lloc * 64 + s * 8);
            }
            v8s a[8];
#pragma unroll
            for (int mi = 0; mi < 8; ++mi) {
                int jloc = jbase + mi * 16 + r;
                a[mi] = *(const v8s*)(wsb + jloc * 64 + s * 8);
            }
#pragma unroll
            for (int mi = 0; mi < 8; ++mi)
#pragma unroll
                for (int nj = 0; nj < 4; ++nj)
                    acc[mi][nj] = __builtin_amdgcn_mfma_f32_16x16x32_bf16(
                        a[mi], b[nj], acc[mi][nj], 0, 0, 0);
        }
    }

    unsigned short* base = (jt == 0 ? q : (jt == 1 ? k : v));

    float bias[8][4];
#pragma unroll
    for (int mi = 0; mi < 8; ++mi)
        *(float4*)bias[mi] = *(const float4*)(bqkv + j0 + jbase + mi * 16 + quad * 4);

    unsigned short* dstp[8];
#pragma unroll
    for (int mi = 0; mi < 8; ++mi) {
        int hh = wr * 4 + (mi >> 1);
        int d0 = (mi & 1) * 16 + quad * 4;
        dstp[mi] = base + (size_t)(n * HH + hh) * LL * DD + d0;
    }

    if (jt < 2) {
#pragma unroll
        for (int nj = 0; nj < 4; ++nj) {
            float t[8][4];
            float ss[4] = {0.f, 0.f, 0.f, 0.f};
#pragma unroll
            for (int mi = 0; mi < 8; ++mi)
#pragma unroll
                for (int reg = 0; reg < 4; ++reg) {
                    float val = acc[mi][nj][reg] + bias[mi][reg];
                    t[mi][reg] = val;
                    ss[mi >> 1] += val * val;
                }
#pragma unroll
            for (int h4 = 0; h4 < 4; ++h4) {
                ss[h4] += __shfl_xor(ss[h4], 16);
                ss[h4] += __shfl_xor(ss[h4], 32);
                ss[h4] = rsqrtf(ss[h4]);
            }
            size_t l = (size_t)(l0 + lbase + nj * 16 + r);
#pragma unroll
            for (int mi = 0; mi < 8; ++mi) {
                float rn = ss[mi >> 1];
                v4us pk;
#pragma unroll
                for (int reg = 0; reg < 4; ++reg) pk[reg] = f2bf(t[mi][reg] * rn);
                *(v4us*)(dstp[mi] + l * DD) = pk;
            }
        }
    } else {
#pragma unroll
        for (int nj = 0; nj < 4; ++nj) {
            size_t l = (size_t)(l0 + lbase + nj * 16 + r);
#pragma unroll
            for (int mi = 0; mi < 8; ++mi) {
                v4us pk;
#pragma unroll
                for (int reg = 0; reg < 4; ++reg)
                    pk[reg] = f2bf(acc[mi][nj][reg] + bias[mi][reg]);
                *(v4us*)(dstp[mi] + l * DD) = pk;
            }
        }
    }
}

// ---------------------------------------------------------------------------
// Kernel 3: attn[n,h,d,e] = sum_l k[n,h,l,d] * v[n,h,l,e]   (unchanged)
// ---------------------------------------------------------------------------
__global__ __launch_bounds__(256) void attn_k(
    const unsigned short* __restrict__ k, const unsigned short* __restrict__ v,
    float* __restrict__ attn)
{
    __shared__ float red[4][1024];
    const int nh = blockIdx.y;
    const int wv = threadIdx.x >> 6;
    const int lane = threadIdx.x & 63;
    const int eg = lane & 7;
    const int dg = lane >> 3;
    const int l0 = blockIdx.x * 512 + wv * 128;
    const unsigned short* kb = k + (size_t)nh * LL * DD;
    const unsigned short* vb = v + (size_t)nh * LL * DD;
    float acc[4][4] = {};
#pragma unroll 4
    for (int l = l0; l < l0 + 128; ++l) {
        v4us k4 = *(const v4us*)(kb + (size_t)l * DD + dg * 4);
        v4us v4 = *(const v4us*)(vb + (size_t)l * DD + eg * 4);
        float ka[4] = {bf2f(k4[0]), bf2f(k4[1]), bf2f(k4[2]), bf2f(k4[3])};
        float va[4] = {bf2f(v4[0]), bf2f(v4[1]), bf2f(v4[2]), bf2f(v4[3])};
#pragma unroll
        for (int dp = 0; dp < 4; ++dp)
#pragma unroll
            for (int ep = 0; ep < 4; ++ep)
                acc[dp][ep] += ka[dp] * va[ep];
    }
#pragma unroll
    for (int dp = 0; dp < 4; ++dp)
#pragma unroll
        for (int ep = 0; ep < 4; ++ep)
            red[wv][(dg * 4 + dp) * 32 + eg * 4 + ep] = acc[dp][ep];
    __syncthreads();
    float* ap = attn + (size_t)nh * 1024;
    for (int i = threadIdx.x; i < 1024; i += 256)
        atomicAdd(&ap[i], red[0][i] + red[1][i] + red[2][i] + red[3][i]);
}

// ---------------------------------------------------------------------------
// Kernel 4 (fused mid + proj): unchanged from round 1.
// ---------------------------------------------------------------------------
#define PTOK 64
#define VTP 40
__global__ __launch_bounds__(256, 2) void midproj_k(
    const unsigned short* __restrict__ q, const unsigned short* __restrict__ v,
    const float* __restrict__ attn, const float* __restrict__ wd,
    const unsigned short* __restrict__ wpb, const float* __restrict__ bp,
    float* __restrict__ out)
{
    __shared__ __align__(16) unsigned short vt[8 * 72 * VTP];   // [h][row][40]
    __shared__ __align__(16) unsigned short smid[4 * 64 * 64];  // [chunk][l][64] swz

    const int n  = blockIdx.y;
    const int l0 = blockIdx.x * PTOK;
    const int tid = threadIdx.x;
    const int lane = tid & 63, wave = tid >> 6;
    const int r = lane & 15, quad = lane >> 4;

    // ---- stage v halo for all 8 heads ----
    const unsigned short* vbase = v + (size_t)(n * HH) * LL * DD;
#pragma unroll
    for (int it = 0; it < 9; ++it) {
        int task = it * 256 + tid;            // 2304 = 8h * 72rows * 4segs
        int seg = task & 3;
        int hr = task >> 2;                   // h*72 + row
        int row = hr % 72;
        int h = hr / 72;
        int l = l0 - 4 + row;
        v8u val;
        if (l >= 0 && l < LL)
            val = *(const v8u*)(vbase + ((size_t)h * LL + l) * DD + seg * 8);
        else
            val = (v8u)(unsigned short)0;
        *(v8u*)(&vt[hr * VTP + seg * 8]) = val;
    }
    __syncthreads();

    const float inv_pi = 0.31830988618379067f;
#pragma unroll
    for (int hi = 0; hi < 2; ++hi) {
        const int h = wave * 2 + hi;
        const int nh = n * HH + h;
        const unsigned short* qb = q + (size_t)nh * LL * DD;
        const unsigned short* vth = vt + h * 72 * VTP;

        v8s bfrag[2];
#pragma unroll
        for (int et = 0; et < 2; ++et) {
            int e = et * 16 + r;
#pragma unroll
            for (int j = 0; j < 8; ++j)
                ((unsigned short*)&bfrag[et])[j] =
                    f2bf(attn[(size_t)nh * 1024 + (quad * 8 + j) * 32 + e]);
        }
        float wc[9];
#pragma unroll
        for (int r9 = 0; r9 < 9; ++r9) wc[r9] = wd[h * 9 + r9];

#pragma unroll
        for (int lt = 0; lt < 4; ++lt) {
            const int tb = lt * 16;
            v8s afrag = *(const v8s*)(qb + (size_t)(l0 + tb + r) * DD + quad * 8);
            v4f acc[2] = {(v4f)(0.f), (v4f)(0.f)};
#pragma unroll
            for (int et = 0; et < 2; ++et)
                acc[et] = __builtin_amdgcn_mfma_f32_16x16x32_bf16(
                    afrag, bfrag[et], acc[et], 0, 0, 0);

            float vcol[2][12];
#pragma unroll
            for (int et = 0; et < 2; ++et) {
                int e = et * 16 + r;
#pragma unroll
                for (int o = 0; o < 12; ++o)
                    vcol[et][o] = bf2f(vth[(tb + quad * 4 + o) * VTP + e]);
            }

            float t[2][4], ss[4];
#pragma unroll
            for (int reg = 0; reg < 4; ++reg) {
                t[0][reg] = 0.5f * vcol[0][4 + reg] + inv_pi * acc[0][reg];
                t[1][reg] = 0.5f * vcol[1][4 + reg] + inv_pi * acc[1][reg];
                ss[reg] = t[0][reg] * t[0][reg] + t[1][reg] * t[1][reg];
            }
#pragma unroll
            for (int m = 1; m < 16; m <<= 1)
#pragma unroll
                for (int reg = 0; reg < 4; ++reg)
                    ss[reg] += __shfl_xor(ss[reg], m);
#pragma unroll
            for (int reg = 0; reg < 4; ++reg) ss[reg] = rsqrtf(ss[reg]);

#pragma unroll
            for (int et = 0; et < 2; ++et) {
                int c = h * 32 + et * 16 + r;
                int chunk = c >> 6, c6 = c & 63;
                int goff = c6 & 7;
#pragma unroll
                for (int reg = 0; reg < 4; ++reg) {
                    float dv = 0.f;
#pragma unroll
                    for (int r9 = 0; r9 < 9; ++r9) dv += wc[r9] * vcol[et][reg + r9];
                    int l = tb + quad * 4 + reg;
                    int g = (c6 >> 3) ^ (l & 7);
                    smid[chunk * 4096 + l * 64 + g * 8 + goff] =
                        f2bf(t[et][reg] * ss[reg] + dv);
                }
            }
        }
    }
    __syncthreads();

    // ---- proj phase (no barriers) ----
    const int jbase = wave * 64;
    v4f acc[4][4];
#pragma unroll
    for (int mi = 0; mi < 4; ++mi)
#pragma unroll
        for (int nj = 0; nj < 4; ++nj) acc[mi][nj] = (v4f)(0.f);

#pragma unroll
    for (int kt = 0; kt < 4; ++kt) {
        v8s a[4][2], b[4][2];
#pragma unroll
        for (int kk = 0; kk < 2; ++kk) {
            const int cfrag = kk * 4 + quad;
#pragma unroll
            for (int mi = 0; mi < 4; ++mi) {
                int j = jbase + mi * 16 + r;
                a[mi][kk] = *(const v8s*)(wpb + (size_t)j * CC + kt * 64 + cfrag * 8);
            }
            const int s = cfrag ^ (r & 7);
#pragma unroll
            for (int nj = 0; nj < 4; ++nj) {
                int lloc = nj * 16 + r;
                b[nj][kk] = *(const v8s*)(smid + kt * 4096 + lloc * 64 + s * 8);
            }
        }
#pragma unroll
        for (int kk = 0; kk < 2; ++kk)
#pragma unroll
            for (int mi = 0; mi < 4; ++mi)
#pragma unroll
                for (int nj = 0; nj < 4; ++nj)
                    acc[mi][nj] = __builtin_amdgcn_mfma_f32_16x16x32_bf16(
                        a[mi][kk], b[nj][kk], acc[mi][nj], 0, 0, 0);
    }

#pragma unroll
    for (int mi = 0; mi < 4; ++mi)
#pragma unroll
        for (int reg = 0; reg < 4; ++reg) {
            int j = jbase + mi * 16 + quad * 4 + reg;
            float bias = bp[j];
#pragma unroll
            for (int nj = 0; nj < 4; ++nj) {
                int l = l0 + nj * 16 + r;
                out[((size_t)n * CC + j) * LL + l] = acc[mi][nj][reg] + bias;
            }
        }
}

// ---------------------------------------------------------------------------
extern "C" void kernel_launch(void* const* d_in, const int* in_sizes, int n_in,
                              void* d_out, int out_size, void* d_ws, size_t ws_size,
                              hipStream_t stream)
{
    const float* x     = (const float*)d_in[0];
    const float* wqkv  = (const float*)d_in[1];
    const float* bqkv  = (const float*)d_in[2];
    const float* wproj = (const float*)d_in[3];
    const float* bproj = (const float*)d_in[4];
    const float* wd    = (const float*)d_in[5];
    float* out = (float*)d_out;

    const size_t QKV = (size_t)NB * HH * LL * DD;       // 8388608 elems
    unsigned short* q = (unsigned short*)d_ws;
    unsigned short* k = q + QKV;
    unsigned short* v = k + QKV;
    float* attn = (float*)(v + QKV);                    // 65536 floats
    unsigned short* wqb = (unsigned short*)(attn + (size_t)NB * HH * DD * DD);
    unsigned short* wpb = wqb + 3 * CC * CC;

    prep_w<<<128, 256, 0, stream>>>(wqkv, wproj, wqb, wpb);
    gemm_qkv_mfma<<<768, 256, 0, stream>>>(x, wqb, bqkv, q, k, v, attn);
    attn_k<<<dim3(8, 64), 256, 0, stream>>>(k, v, attn);
    midproj_k<<<dim3(LL / PTOK, NB), 256, 0, stream>>>(q, v, attn, wd, wpb, bproj, out);
}

// Round 4
// 150.273 us; speedup vs baseline: 1.0572x; 1.0572x over previous
//
#include <hip/hip_runtime.h>

#define NB 8
#define CC 256
#define HH 8
#define DD 32
#define LL 4096

typedef short v8s __attribute__((ext_vector_type(8)));
typedef float v4f __attribute__((ext_vector_type(4)));
typedef unsigned short v8u __attribute__((ext_vector_type(8)));
typedef unsigned short v4us __attribute__((ext_vector_type(4)));

__device__ __forceinline__ float4 ld4(const float* p) { return *(const float4*)p; }

// round-to-nearest-even fp32 -> bf16 (as ushort)
__device__ __forceinline__ unsigned short f2bf(float f) {
    union { float f; unsigned int u; } v; v.f = f;
    unsigned int r = (v.u + 0x7FFFu + ((v.u >> 16) & 1u)) >> 16;
    return (unsigned short)r;
}
__device__ __forceinline__ float bf2f(unsigned short u) {
    union { unsigned int u; float f; } v; v.u = ((unsigned int)u) << 16;
    return v.f;
}

// async global->LDS, 16 B per lane (dest = wave-uniform base + lane*16)
__device__ __forceinline__ void gl_lds16(const unsigned short* g, unsigned short* l) {
    __builtin_amdgcn_global_load_lds(
        (const __attribute__((address_space(1))) void*)g,
        (__attribute__((address_space(3))) void*)l, 16, 0, 0);
}

// ---------------------------------------------------------------------------
// prep_w: weights fp32 -> bf16 (verbatim round-2).  128 blocks.
// ---------------------------------------------------------------------------
__global__ __launch_bounds__(256) void prep_w(
    const float* __restrict__ wq, const float* __restrict__ wp,
    unsigned short* __restrict__ dwq, unsigned short* __restrict__ dwp)
{
    int ti = blockIdx.x * 256 + threadIdx.x;
    if (ti < 24576) {                       // 3*CC*CC / 8
        int i = ti * 8;
        float4 f0 = ld4(wq + i), f1 = ld4(wq + i + 4);
        v8u o;
        o[0] = f2bf(f0.x); o[1] = f2bf(f0.y); o[2] = f2bf(f0.z); o[3] = f2bf(f0.w);
        o[4] = f2bf(f1.x); o[5] = f2bf(f1.y); o[6] = f2bf(f1.z); o[7] = f2bf(f1.w);
        *(v8u*)(dwq + i) = o;
    } else {                                // CC*CC / 8
        int i = (ti - 24576) * 8;
        float4 f0 = ld4(wp + i), f1 = ld4(wp + i + 4);
        v8u o;
        o[0] = f2bf(f0.x); o[1] = f2bf(f0.y); o[2] = f2bf(f0.z); o[3] = f2bf(f0.w);
        o[4] = f2bf(f1.x); o[5] = f2bf(f1.y); o[6] = f2bf(f1.z); o[7] = f2bf(f1.w);
        *(v8u*)(dwp + i) = o;
    }
}

// ---------------------------------------------------------------------------
// Kernel 1: qkv GEMM, restructured.  Block = one (64 l, n) tile; X transposed
// + staged ONCE (full K=256, 32 KB, XOR-swizzled: logical chunk o stored at
// phys o^(row&7), matching read s = cfrag^(r&7)); the three jt (q/k/v) loop
// in-block streaming W tiles via global_load_lds (pre-swizzled source, linear
// LDS dest).  acc 4x4 = 64 AGPR.  Grid 512 = exactly 2 blocks/CU, no tail.
// Per-head L2 norm fused for q/k epilogues (verbatim round-2 math).
// Blocks < 256 also zero the attn accumulator (stream-ordered before attn_k).
// ---------------------------------------------------------------------------
__global__ __launch_bounds__(256, 2) void gemm_qkv_mfma(
    const float* __restrict__ x, const unsigned short* __restrict__ wqb,
    const float* __restrict__ bqkv,
    unsigned short* __restrict__ q, unsigned short* __restrict__ k,
    unsigned short* __restrict__ v, float* __restrict__ attn)
{
    __shared__ __align__(16) unsigned short xsf[16384];  // 64 l x 256 c (swz)
    __shared__ __align__(16) unsigned short wsb[16384];  // 256 j x 64 c (swz)

    const int bid = blockIdx.x;
    const int l0 = (bid & 63) * 64;
    const int n  = bid >> 6;
    const int tid = threadIdx.x;
    const int lane = tid & 63, wave = tid >> 6;
    const int r = lane & 15, quad = lane >> 4;

    if (bid < 256) attn[bid * 256 + tid] = 0.f;

    // ---- stage X once: transpose-gather fp32 -> bf16, swizzled ----
    {
        const int lx = tid & 63, cq = tid >> 6;
        const float* xcol = x + (size_t)n * CC * LL + l0 + lx;
        unsigned short* xrow = xsf + lx * 256;
#pragma unroll
        for (int i = 0; i < 8; ++i) {
            const float* src = xcol + (size_t)(cq * 8 + i) * 8 * LL;
            float f[8];
#pragma unroll
            for (int j = 0; j < 8; ++j) f[j] = src[(size_t)j * LL];
            v8u o;
#pragma unroll
            for (int j = 0; j < 8; ++j) o[j] = f2bf(f[j]);
            *(v8u*)(xrow + (cq * 8 + (i ^ (lx & 7))) * 8) = o;
        }
    }

    const int srow = wave * 8 + (lane >> 3);
    const int dchunk = (lane & 7) ^ (lane >> 3);
    unsigned short* wls = wsb + wave * 512 + lane * 8;
    const int jbase = wave * 64;

    for (int jt = 0; jt < 3; ++jt) {
        const int j0 = jt * 256;
        const unsigned short* wg = wqb + (size_t)(j0 + srow) * CC + dchunk * 8;

        v4f acc[4][4];
#pragma unroll
        for (int mi = 0; mi < 4; ++mi)
#pragma unroll
            for (int nj = 0; nj < 4; ++nj) acc[mi][nj] = (v4f)(0.f);

        for (int kt = 0; kt < 4; ++kt) {
            __syncthreads();   // prior readers of wsb done (covers X stage 1st time)
#pragma unroll
            for (int i = 0; i < 8; ++i)
                gl_lds16(wg + (size_t)i * 32 * CC + kt * 64, wls + i * 2048);
            __syncthreads();   // W tile visible

#pragma unroll
            for (int kk = 0; kk < 2; ++kk) {
                const int cfrag = kk * 4 + quad;
                const int s = cfrag ^ (r & 7);
                v8s b[4];
#pragma unroll
                for (int nj = 0; nj < 4; ++nj)
                    b[nj] = *(const v8s*)(xsf + (nj * 16 + r) * 256 + kt * 64 + s * 8);
                v8s a[4];
#pragma unroll
                for (int mi = 0; mi < 4; ++mi)
                    a[mi] = *(const v8s*)(wsb + (jbase + mi * 16 + r) * 64 + s * 8);
#pragma unroll
                for (int mi = 0; mi < 4; ++mi)
#pragma unroll
                    for (int nj = 0; nj < 4; ++nj)
                        acc[mi][nj] = __builtin_amdgcn_mfma_f32_16x16x32_bf16(
                            a[mi], b[nj], acc[mi][nj], 0, 0, 0);
            }
        }

        // ---- epilogue for this jt ----
        unsigned short* basep = (jt == 0 ? q : (jt == 1 ? k : v));
        float bias[4][4];
#pragma unroll
        for (int mi = 0; mi < 4; ++mi)
            *(float4*)bias[mi] = *(const float4*)(bqkv + j0 + jbase + mi * 16 + quad * 4);

        unsigned short* dstp[4];
#pragma unroll
        for (int mi = 0; mi < 4; ++mi) {
            int hh = wave * 2 + (mi >> 1);
            int d0 = (mi & 1) * 16 + quad * 4;
            dstp[mi] = basep + (size_t)(n * HH + hh) * LL * DD + d0;
        }

        if (jt < 2) {
#pragma unroll
            for (int nj = 0; nj < 4; ++nj) {
                float t[4][4];
                float ss[2] = {0.f, 0.f};
#pragma unroll
                for (int mi = 0; mi < 4; ++mi)
#pragma unroll
                    for (int reg = 0; reg < 4; ++reg) {
                        float val = acc[mi][nj][reg] + bias[mi][reg];
                        t[mi][reg] = val;
                        ss[mi >> 1] += val * val;
                    }
#pragma unroll
                for (int g2 = 0; g2 < 2; ++g2) {
                    ss[g2] += __shfl_xor(ss[g2], 16);
                    ss[g2] += __shfl_xor(ss[g2], 32);
                    ss[g2] = rsqrtf(ss[g2]);
                }
                size_t l = (size_t)(l0 + nj * 16 + r);
#pragma unroll
                for (int mi = 0; mi < 4; ++mi) {
                    float rn = ss[mi >> 1];
                    v4us pk;
#pragma unroll
                    for (int reg = 0; reg < 4; ++reg) pk[reg] = f2bf(t[mi][reg] * rn);
                    *(v4us*)(dstp[mi] + l * DD) = pk;
                }
            }
        } else {
#pragma unroll
            for (int nj = 0; nj < 4; ++nj) {
                size_t l = (size_t)(l0 + nj * 16 + r);
#pragma unroll
                for (int mi = 0; mi < 4; ++mi) {
                    v4us pk;
#pragma unroll
                    for (int reg = 0; reg < 4; ++reg)
                        pk[reg] = f2bf(acc[mi][nj][reg] + bias[mi][reg]);
                    *(v4us*)(dstp[mi] + l * DD) = pk;
                }
            }
        }
    }
}

// ---------------------------------------------------------------------------
// Kernel 3: attn[n,h,d,e] = sum_l k[n,h,l,d] * v[n,h,l,e]   (verbatim)
// ---------------------------------------------------------------------------
__global__ __launch_bounds__(256) void attn_k(
    const unsigned short* __restrict__ k, const unsigned short* __restrict__ v,
    float* __restrict__ attn)
{
    __shared__ float red[4][1024];
    const int nh = blockIdx.y;
    const int wv = threadIdx.x >> 6;
    const int lane = threadIdx.x & 63;
    const int eg = lane & 7;
    const int dg = lane >> 3;
    const int l0 = blockIdx.x * 512 + wv * 128;
    const unsigned short* kb = k + (size_t)nh * LL * DD;
    const unsigned short* vb = v + (size_t)nh * LL * DD;
    float acc[4][4] = {};
#pragma unroll 4
    for (int l = l0; l < l0 + 128; ++l) {
        v4us k4 = *(const v4us*)(kb + (size_t)l * DD + dg * 4);
        v4us v4 = *(const v4us*)(vb + (size_t)l * DD + eg * 4);
        float ka[4] = {bf2f(k4[0]), bf2f(k4[1]), bf2f(k4[2]), bf2f(k4[3])};
        float va[4] = {bf2f(v4[0]), bf2f(v4[1]), bf2f(v4[2]), bf2f(v4[3])};
#pragma unroll
        for (int dp = 0; dp < 4; ++dp)
#pragma unroll
            for (int ep = 0; ep < 4; ++ep)
                acc[dp][ep] += ka[dp] * va[ep];
    }
#pragma unroll
    for (int dp = 0; dp < 4; ++dp)
#pragma unroll
        for (int ep = 0; ep < 4; ++ep)
            red[wv][(dg * 4 + dp) * 32 + eg * 4 + ep] = acc[dp][ep];
    __syncthreads();
    float* ap = attn + (size_t)nh * 1024;
    for (int i = threadIdx.x; i < 1024; i += 256)
        atomicAdd(&ap[i], red[0][i] + red[1][i] + red[2][i] + red[3][i]);
}

// ---------------------------------------------------------------------------
// Kernel 4 (fused mid + proj): verbatim round-2.
// ---------------------------------------------------------------------------
#define PTOK 64
#define VTP 40
__global__ __launch_bounds__(256, 2) void midproj_k(
    const unsigned short* __restrict__ q, const unsigned short* __restrict__ v,
    const float* __restrict__ attn, const float* __restrict__ wd,
    const unsigned short* __restrict__ wpb, const float* __restrict__ bp,
    float* __restrict__ out)
{
    __shared__ __align__(16) unsigned short vt[8 * 72 * VTP];   // [h][row][40]
    __shared__ __align__(16) unsigned short smid[4 * 64 * 64];  // [chunk][l][64] swz

    const int n  = blockIdx.y;
    const int l0 = blockIdx.x * PTOK;
    const int tid = threadIdx.x;
    const int lane = tid & 63, wave = tid >> 6;
    const int r = lane & 15, quad = lane >> 4;

    // ---- stage v halo for all 8 heads ----
    const unsigned short* vbase = v + (size_t)(n * HH) * LL * DD;
#pragma unroll
    for (int it = 0; it < 9; ++it) {
        int task = it * 256 + tid;            // 2304 = 8h * 72rows * 4segs
        int seg = task & 3;
        int hr = task >> 2;                   // h*72 + row
        int row = hr % 72;
        int h = hr / 72;
        int l = l0 - 4 + row;
        v8u val;
        if (l >= 0 && l < LL)
            val = *(const v8u*)(vbase + ((size_t)h * LL + l) * DD + seg * 8);
        else
            val = (v8u)(unsigned short)0;
        *(v8u*)(&vt[hr * VTP + seg * 8]) = val;
    }
    __syncthreads();

    const float inv_pi = 0.31830988618379067f;
#pragma unroll
    for (int hi = 0; hi < 2; ++hi) {
        const int h = wave * 2 + hi;
        const int nh = n * HH + h;
        const unsigned short* qb = q + (size_t)nh * LL * DD;
        const unsigned short* vth = vt + h * 72 * VTP;

        v8s bfrag[2];
#pragma unroll
        for (int et = 0; et < 2; ++et) {
            int e = et * 16 + r;
#pragma unroll
            for (int j = 0; j < 8; ++j)
                ((unsigned short*)&bfrag[et])[j] =
                    f2bf(attn[(size_t)nh * 1024 + (quad * 8 + j) * 32 + e]);
        }
        float wc[9];
#pragma unroll
        for (int r9 = 0; r9 < 9; ++r9) wc[r9] = wd[h * 9 + r9];

#pragma unroll
        for (int lt = 0; lt < 4; ++lt) {
            const int tb = lt * 16;
            v8s afrag = *(const v8s*)(qb + (size_t)(l0 + tb + r) * DD + quad * 8);
            v4f acc[2] = {(v4f)(0.f), (v4f)(0.f)};
#pragma unroll
            for (int et = 0; et < 2; ++et)
                acc[et] = __builtin_amdgcn_mfma_f32_16x16x32_bf16(
                    afrag, bfrag[et], acc[et], 0, 0, 0);

            float vcol[2][12];
#pragma unroll
            for (int et = 0; et < 2; ++et) {
                int e = et * 16 + r;
#pragma unroll
                for (int o = 0; o < 12; ++o)
                    vcol[et][o] = bf2f(vth[(tb + quad * 4 + o) * VTP + e]);
            }

            float t[2][4], ss[4];
#pragma unroll
            for (int reg = 0; reg < 4; ++reg) {
                t[0][reg] = 0.5f * vcol[0][4 + reg] + inv_pi * acc[0][reg];
                t[1][reg] = 0.5f * vcol[1][4 + reg] + inv_pi * acc[1][reg];
                ss[reg] = t[0][reg] * t[0][reg] + t[1][reg] * t[1][reg];
            }
#pragma unroll
            for (int m = 1; m < 16; m <<= 1)
#pragma unroll
                for (int reg = 0; reg < 4; ++reg)
                    ss[reg] += __shfl_xor(ss[reg], m);
#pragma unroll
            for (int reg = 0; reg < 4; ++reg) ss[reg] = rsqrtf(ss[reg]);

#pragma unroll
            for (int et = 0; et < 2; ++et) {
                int c = h * 32 + et * 16 + r;
                int chunk = c >> 6, c6 = c & 63;
                int goff = c6 & 7;
#pragma unroll
                for (int reg = 0; reg < 4; ++reg) {
                    float dv = 0.f;
#pragma unroll
                    for (int r9 = 0; r9 < 9; ++r9) dv += wc[r9] * vcol[et][reg + r9];
                    int l = tb + quad * 4 + reg;
                    int g = (c6 >> 3) ^ (l & 7);
                    smid[chunk * 4096 + l * 64 + g * 8 + goff] =
                        f2bf(t[et][reg] * ss[reg] + dv);
                }
            }
        }
    }
    __syncthreads();

    // ---- proj phase (no barriers) ----
    const int jbase = wave * 64;
    v4f acc[4][4];
#pragma unroll
    for (int mi = 0; mi < 4; ++mi)
#pragma unroll
        for (int nj = 0; nj < 4; ++nj) acc[mi][nj] = (v4f)(0.f);

#pragma unroll
    for (int kt = 0; kt < 4; ++kt) {
        v8s a[4][2], b[4][2];
#pragma unroll
        for (int kk = 0; kk < 2; ++kk) {
            const int cfrag = kk * 4 + quad;
#pragma unroll
            for (int mi = 0; mi < 4; ++mi) {
                int j = jbase + mi * 16 + r;
                a[mi][kk] = *(const v8s*)(wpb + (size_t)j * CC + kt * 64 + cfrag * 8);
            }
            const int s = cfrag ^ (r & 7);
#pragma unroll
            for (int nj = 0; nj < 4; ++nj) {
                int lloc = nj * 16 + r;
                b[nj][kk] = *(const v8s*)(smid + kt * 4096 + lloc * 64 + s * 8);
            }
        }
#pragma unroll
        for (int kk = 0; kk < 2; ++kk)
#pragma unroll
            for (int mi = 0; mi < 4; ++mi)
#pragma unroll
                for (int nj = 0; nj < 4; ++nj)
                    acc[mi][nj] = __builtin_amdgcn_mfma_f32_16x16x32_bf16(
                        a[mi][kk], b[nj][kk], acc[mi][nj], 0, 0, 0);
    }

#pragma unroll
    for (int mi = 0; mi < 4; ++mi)
#pragma unroll
        for (int reg = 0; reg < 4; ++reg) {
            int j = jbase + mi * 16 + quad * 4 + reg;
            float bias = bp[j];
#pragma unroll
            for (int nj = 0; nj < 4; ++nj) {
                int l = l0 + nj * 16 + r;
                out[((size_t)n * CC + j) * LL + l] = acc[mi][nj][reg] + bias;
            }
        }
}

// ---------------------------------------------------------------------------
extern "C" void kernel_launch(void* const* d_in, const int* in_sizes, int n_in,
                              void* d_out, int out_size, void* d_ws, size_t ws_size,
                              hipStream_t stream)
{
    const float* x     = (const float*)d_in[0];
    const float* wqkv  = (const float*)d_in[1];
    const float* bqkv  = (const float*)d_in[2];
    const float* wproj = (const float*)d_in[3];
    const float* bproj = (const float*)d_in[4];
    const float* wd    = (const float*)d_in[5];
    float* out = (float*)d_out;

    const size_t QKV = (size_t)NB * HH * LL * DD;       // 8388608 elems
    unsigned short* q = (unsigned short*)d_ws;
    unsigned short* k = q + QKV;
    unsigned short* v = k + QKV;
    float* attn = (float*)(v + QKV);                    // 65536 floats
    unsigned short* wqb = (unsigned short*)(attn + (size_t)NB * HH * DD * DD);
    unsigned short* wpb = wqb + 3 * CC * CC;

    prep_w<<<128, 256, 0, stream>>>(wqkv, wproj, wqb, wpb);
    gemm_qkv_mfma<<<512, 256, 0, stream>>>(x, wqb, bqkv, q, k, v, attn);
    attn_k<<<dim3(8, 64), 256, 0, stream>>>(k, v, attn);
    midproj_k<<<dim3(LL / PTOK, NB), 256, 0, stream>>>(q, v, attn, wd, wpb, bproj, out);
}